// Round 1
// baseline (75.671 us; speedup 1.0000x reference)
//
#include <hip/hip_runtime.h>
#include <hip/hip_bf16.h>

typedef unsigned short u16;
typedef unsigned int u32;
typedef __attribute__((ext_vector_type(8))) short short8;   // 8 bf16 fragment (4 VGPRs)
typedef __attribute__((ext_vector_type(8))) u16 ushort8;
typedef __attribute__((ext_vector_type(4))) float f32x4;

#define B_SZ 4096
#define D_SZ 512
#define NCLS 64

// ---------------- helpers ----------------

__device__ __forceinline__ u16 f2bf(float x) {
    union { float f; u32 u; } a; a.f = x;
    u32 r = a.u + 0x7fffu + ((a.u >> 16) & 1u);   // round-to-nearest-even
    return (u16)(r >> 16);
}

__device__ __forceinline__ void gload16(const void* g, void* l) {
    // async global -> LDS, 16 bytes per lane; LDS dest = wave-uniform base + lane*16
    __builtin_amdgcn_global_load_lds(
        (const __attribute__((address_space(1))) u32*)g,
        (__attribute__((address_space(3))) u32*)l,
        16, 0, 0);
}

// ---------------- kernel 0: init workspace ----------------

__global__ void init_kernel(float* ap_sum, u32* an_min, int* counts, float* out) {
    int i = blockIdx.x * 256 + threadIdx.x;
    if (i < B_SZ) { ap_sum[i] = 0.0f; an_min[i] = 0x7f800000u; }  // +inf bits
    if (i < NCLS) counts[i] = 0;
    if (i == 0) out[0] = 0.0f;
}

// ---------------- kernel 1: fp32->bf16 copy, row sq-norms, class histogram ----------------

__global__ void prep_kernel(const float* __restrict__ in, const int* __restrict__ lab,
                            u16* __restrict__ bfout, float* __restrict__ sq,
                            int* __restrict__ counts) {
    int row = blockIdx.x;       // 4096 blocks, 64 threads (1 wave)
    int l = threadIdx.x;
    const float* p = in + (size_t)row * D_SZ + l * 8;
    float4 v0 = *(const float4*)p;
    float4 v1 = *(const float4*)(p + 4);
    float s = v0.x*v0.x + v0.y*v0.y + v0.z*v0.z + v0.w*v0.w
            + v1.x*v1.x + v1.y*v1.y + v1.z*v1.z + v1.w*v1.w;
    ushort8 o;
    o[0]=f2bf(v0.x); o[1]=f2bf(v0.y); o[2]=f2bf(v0.z); o[3]=f2bf(v0.w);
    o[4]=f2bf(v1.x); o[5]=f2bf(v1.y); o[6]=f2bf(v1.z); o[7]=f2bf(v1.w);
    *(ushort8*)(bfout + (size_t)row * D_SZ + l * 8) = o;
    #pragma unroll
    for (int off = 1; off < 64; off <<= 1) s += __shfl_xor(s, off);
    if (l == 0) {
        sq[row] = s;
        atomicAdd(&counts[lab[row]], 1);
    }
}

// ---------------- kernel 2: fused Gram + distance + masked row reductions ----------------

__global__ __launch_bounds__(256) void tile_kernel(
    const u16* __restrict__ bfin, const int* __restrict__ lab,
    const float* __restrict__ sq, float* __restrict__ ap_sum, u32* __restrict__ an_min)
{
    __shared__ u16 As[128 * 32];
    __shared__ u16 Bs[128 * 32];
    __shared__ float sqA[128], sqB[128];
    __shared__ int labA[128], labB[128];

    const int t = threadIdx.x;
    const int tm = blockIdx.x & 31;
    const int tn = blockIdx.x >> 5;
    const int rowBase = tm * 128;
    const int colBase = tn * 128;

    if (t < 128) { labA[t] = lab[rowBase + t]; sqA[t] = sq[rowBase + t]; }
    else { int u = t - 128; labB[u] = lab[colBase + u]; sqB[u] = sq[colBase + u]; }

    const int wave = t >> 6, lane = t & 63;
    const int wr = wave >> 1, wc = wave & 1;
    const int g = lane >> 4, c = lane & 15;

    f32x4 acc[4][4];
    #pragma unroll
    for (int i = 0; i < 4; ++i)
        #pragma unroll
        for (int j = 0; j < 4; ++j)
            acc[i][j] = (f32x4){0.f, 0.f, 0.f, 0.f};

    const u16* gA = bfin + (size_t)(rowBase + (t >> 2)) * D_SZ + (t & 3) * 8;
    const u16* gB = bfin + (size_t)(colBase + (t >> 2)) * D_SZ + (t & 3) * 8;

    #pragma unroll 1
    for (int kk = 0; kk < D_SZ / 32; ++kk) {
        gload16(gA + kk * 32,             As + t * 8);
        gload16(gA + kk * 32 + 64 * D_SZ, As + 2048 + t * 8);
        gload16(gB + kk * 32,             Bs + t * 8);
        gload16(gB + kk * 32 + 64 * D_SZ, Bs + 2048 + t * 8);
        __syncthreads();

        short8 a[4], b[4];
        #pragma unroll
        for (int mi = 0; mi < 4; ++mi)
            a[mi] = *(const short8*)&As[(wr * 64 + mi * 16 + c) * 32 + g * 8];
        #pragma unroll
        for (int ni = 0; ni < 4; ++ni)
            b[ni] = *(const short8*)&Bs[(wc * 64 + ni * 16 + c) * 32 + g * 8];

        #pragma unroll
        for (int mi = 0; mi < 4; ++mi)
            #pragma unroll
            for (int ni = 0; ni < 4; ++ni)
                acc[mi][ni] = __builtin_amdgcn_mfma_f32_16x16x32_bf16(a[mi], b[ni], acc[mi][ni], 0, 0, 0);
        __syncthreads();
    }

    // Epilogue: C/D layout: col = lane&15, row = (lane>>4)*4 + reg
    #pragma unroll
    for (int mi = 0; mi < 4; ++mi) {
        #pragma unroll
        for (int r = 0; r < 4; ++r) {
            const int lrow = wr * 64 + mi * 16 + g * 4 + r;
            const int i = rowBase + lrow;
            const int li = labA[lrow];
            const float sqi = sqA[lrow];
            float s = 0.0f;
            float mn = __builtin_inff();
            #pragma unroll
            for (int ni = 0; ni < 4; ++ni) {
                const int lcol = wc * 64 + ni * 16 + c;
                const int j = colBase + lcol;
                float d2 = sqi + sqB[lcol] - 2.0f * acc[mi][ni][r];
                d2 = fmaxf(d2, 0.0f);
                float dist = (d2 > 1e-12f) ? __builtin_sqrtf(d2) : 0.0f;
                if (i == j) dist = 0.0f;
                if (li == labB[lcol]) s += dist;
                else                  mn = fminf(mn, dist);
            }
            #pragma unroll
            for (int off = 1; off < 16; off <<= 1) {
                s += __shfl_xor(s, off);
                mn = fminf(mn, __shfl_xor(mn, off));
            }
            if (c == 0) {
                atomicAdd(&ap_sum[i], s);
                atomicMin(&an_min[i], __float_as_uint(mn));
            }
        }
    }
}

// ---------------- kernel 3: finalize scalar loss ----------------

__global__ void final_kernel(const float* __restrict__ ap_sum, const u32* __restrict__ an_min,
                             const int* __restrict__ lab, const int* __restrict__ counts,
                             float* __restrict__ out) {
    int i = blockIdx.x * 256 + threadIdx.x;
    float v = 0.0f;
    if (i < B_SZ) {
        float apm = ap_sum[i] / (float)counts[lab[i]];
        float anm = __uint_as_float(an_min[i]);
        float tmp = apm - anm + 1.0f;   // MARGIN = 1.0
        v = fmaxf(tmp, 0.0f);
    }
    #pragma unroll
    for (int off = 1; off < 64; off <<= 1) v += __shfl_xor(v, off);
    __shared__ float wsum[4];
    if ((threadIdx.x & 63) == 0) wsum[threadIdx.x >> 6] = v;
    __syncthreads();
    if (threadIdx.x == 0) atomicAdd(out, wsum[0] + wsum[1] + wsum[2] + wsum[3]);
}

// ---------------- launch ----------------

extern "C" void kernel_launch(void* const* d_in, const int* in_sizes, int n_in,
                              void* d_out, int out_size, void* d_ws, size_t ws_size,
                              hipStream_t stream) {
    const float* inputs = (const float*)d_in[0];
    const int* labels = (const int*)d_in[1];
    float* out = (float*)d_out;

    // workspace layout (needs ~4.3 MB)
    char* ws = (char*)d_ws;
    float* ap_sum = (float*)ws;            // 4096 floats
    u32* an_min = (u32*)(ws + 16384);      // 4096 u32
    int* counts = (int*)(ws + 32768);      // 64 ints
    float* sq = (float*)(ws + 33024);      // 4096 floats
    u16* bfin = (u16*)(ws + 65536);        // 4096*512 bf16 = 4 MB

    init_kernel<<<dim3(16), dim3(256), 0, stream>>>(ap_sum, an_min, counts, out);
    prep_kernel<<<dim3(B_SZ), dim3(64), 0, stream>>>(inputs, labels, bfin, sq, counts);
    tile_kernel<<<dim3(1024), dim3(256), 0, stream>>>(bfin, labels, sq, ap_sum, an_min);
    final_kernel<<<dim3(16), dim3(256), 0, stream>>>(ap_sum, an_min, labels, counts, out);
}

// Round 2
// 43.647 us; speedup vs baseline: 1.7337x; 1.7337x over previous
//
#include <hip/hip_runtime.h>
#include <hip/hip_bf16.h>

typedef unsigned short u16;
typedef unsigned int u32;
typedef __attribute__((ext_vector_type(8))) short short8;   // 8 bf16 fragment (4 VGPRs)
typedef __attribute__((ext_vector_type(8))) u16 ushort8;
typedef __attribute__((ext_vector_type(4))) float f32x4;

#define B_SZ 4096
#define D_SZ 512
#define NCLS 64
#define NT   32                      // 4096/128 tiles per dimension
#define NBLK (NT * (NT + 1) / 2)     // 528 lower-triangular tiles

// ---------------- helpers ----------------

__device__ __forceinline__ u16 f2bf(float x) {
    union { float f; u32 u; } a; a.f = x;
    u32 r = a.u + 0x7fffu + ((a.u >> 16) & 1u);   // round-to-nearest-even
    return (u16)(r >> 16);
}

__device__ __forceinline__ void gload16(const void* g, void* l) {
    // async global -> LDS, 16 bytes per lane; LDS dest = wave-uniform base + lane*16
    __builtin_amdgcn_global_load_lds(
        (const __attribute__((address_space(1))) u32*)g,
        (__attribute__((address_space(3))) u32*)l,
        16, 0, 0);
}

// ---------------- kernel 1: fp32->bf16 copy, row sq-norms, accumulator init ----------------
// 1024 blocks x 256 threads; each wave owns one row (64 lanes x 8 floats = 512).

__global__ __launch_bounds__(256) void prep_kernel(
    const float* __restrict__ in, u16* __restrict__ bfout,
    float* __restrict__ sq, float* __restrict__ ap_sum, u32* __restrict__ an_min)
{
    const int wave = threadIdx.x >> 6, l = threadIdx.x & 63;
    const int row = blockIdx.x * 4 + wave;
    const float* p = in + (size_t)row * D_SZ + l * 8;
    float4 v0 = *(const float4*)p;
    float4 v1 = *(const float4*)(p + 4);
    float s = v0.x*v0.x + v0.y*v0.y + v0.z*v0.z + v0.w*v0.w
            + v1.x*v1.x + v1.y*v1.y + v1.z*v1.z + v1.w*v1.w;
    ushort8 o;
    o[0]=f2bf(v0.x); o[1]=f2bf(v0.y); o[2]=f2bf(v0.z); o[3]=f2bf(v0.w);
    o[4]=f2bf(v1.x); o[5]=f2bf(v1.y); o[6]=f2bf(v1.z); o[7]=f2bf(v1.w);
    *(ushort8*)(bfout + (size_t)row * D_SZ + l * 8) = o;
    #pragma unroll
    for (int off = 1; off < 64; off <<= 1) s += __shfl_xor(s, off);
    if (l == 0) {
        sq[row] = s;
        ap_sum[row] = 0.0f;
        an_min[row] = 0x7f800000u;   // +inf bits
    }
}

// ---------------- kernel 2: fused Gram + distance + masked reductions (triangular) ----------------
// 528 blocks, one per lower-triangular 128x128 tile. Off-diagonal blocks reduce
// BOTH row-side (anchor i) and column-side (anchor j, by symmetry dist(i,j)=dist(j,i)).

__global__ __launch_bounds__(256) void tile_kernel(
    const u16* __restrict__ bfin, const int* __restrict__ lab,
    const float* __restrict__ sq, float* __restrict__ ap_sum, u32* __restrict__ an_min)
{
    __shared__ u16 As[128 * 32];
    __shared__ u16 Bs[128 * 32];
    __shared__ float sqA[128], sqB[128];
    __shared__ int labA[128], labB[128];

    const int t = threadIdx.x;

    // triangular decode: bid -> (tm, tn), tm >= tn
    const int bid = blockIdx.x;
    int tm = (int)((__builtin_sqrtf(8.0f * (float)bid + 1.0f) - 1.0f) * 0.5f);
    while ((tm + 1) * (tm + 2) / 2 <= bid) ++tm;
    while (tm * (tm + 1) / 2 > bid) --tm;
    const int tn = bid - tm * (tm + 1) / 2;
    const bool diag = (tm == tn);

    const int rowBase = tm * 128;
    const int colBase = tn * 128;

    if (t < 128) { labA[t] = lab[rowBase + t]; sqA[t] = sq[rowBase + t]; }
    else { int u = t - 128; labB[u] = lab[colBase + u]; sqB[u] = sq[colBase + u]; }

    const int wave = t >> 6, lane = t & 63;
    const int wr = wave >> 1, wc = wave & 1;
    const int g = lane >> 4, c = lane & 15;

    f32x4 acc[4][4];
    #pragma unroll
    for (int i = 0; i < 4; ++i)
        #pragma unroll
        for (int j = 0; j < 4; ++j)
            acc[i][j] = (f32x4){0.f, 0.f, 0.f, 0.f};

    const u16* gA = bfin + (size_t)(rowBase + (t >> 2)) * D_SZ + (t & 3) * 8;
    const u16* gB = bfin + (size_t)(colBase + (t >> 2)) * D_SZ + (t & 3) * 8;

    #pragma unroll 1
    for (int kk = 0; kk < D_SZ / 32; ++kk) {
        gload16(gA + kk * 32,             As + t * 8);
        gload16(gA + kk * 32 + 64 * D_SZ, As + 2048 + t * 8);
        gload16(gB + kk * 32,             Bs + t * 8);
        gload16(gB + kk * 32 + 64 * D_SZ, Bs + 2048 + t * 8);
        __syncthreads();

        short8 a[4], b[4];
        #pragma unroll
        for (int mi = 0; mi < 4; ++mi)
            a[mi] = *(const short8*)&As[(wr * 64 + mi * 16 + c) * 32 + g * 8];
        #pragma unroll
        for (int ni = 0; ni < 4; ++ni)
            b[ni] = *(const short8*)&Bs[(wc * 64 + ni * 16 + c) * 32 + g * 8];

        #pragma unroll
        for (int mi = 0; mi < 4; ++mi)
            #pragma unroll
            for (int ni = 0; ni < 4; ++ni)
                acc[mi][ni] = __builtin_amdgcn_mfma_f32_16x16x32_bf16(a[mi], b[ni], acc[mi][ni], 0, 0, 0);
        __syncthreads();
    }

    // Epilogue. C/D layout: col = lane&15, row = (lane>>4)*4 + reg.
    // Column-side per-thread accumulators (per ni, summed over the 16 (mi,r) rows this thread holds).
    float sc[4], mc[4];
    #pragma unroll
    for (int ni = 0; ni < 4; ++ni) { sc[ni] = 0.0f; mc[ni] = __builtin_inff(); }

    #pragma unroll
    for (int mi = 0; mi < 4; ++mi) {
        #pragma unroll
        for (int r = 0; r < 4; ++r) {
            const int lrow = wr * 64 + mi * 16 + g * 4 + r;
            const int i = rowBase + lrow;
            const int li = labA[lrow];
            const float sqi = sqA[lrow];
            float s = 0.0f;
            float mn = __builtin_inff();
            #pragma unroll
            for (int ni = 0; ni < 4; ++ni) {
                const int lcol = wc * 64 + ni * 16 + c;
                float d2 = sqi + sqB[lcol] - 2.0f * acc[mi][ni][r];
                d2 = fmaxf(d2, 0.0f);
                float dist = (d2 > 1e-12f) ? __builtin_sqrtf(d2) : 0.0f;
                if (diag && lrow == lcol) dist = 0.0f;   // self distance exactly 0
                if (li == labB[lcol]) { s += dist; sc[ni] += dist; }
                else                  { mn = fminf(mn, dist); mc[ni] = fminf(mc[ni], dist); }
            }
            // row-side: reduce across the 16 c-lanes of this g-group
            #pragma unroll
            for (int off = 1; off < 16; off <<= 1) {
                s += __shfl_xor(s, off);
                mn = fminf(mn, __shfl_xor(mn, off));
            }
            if (c == 0) {
                atomicAdd(&ap_sum[i], s);
                atomicMin(&an_min[i], __float_as_uint(mn));   // dist >= 0: uint order == float order
            }
        }
    }

    if (!diag) {
        // column-side: reduce across the 4 g-groups (this wave's 64 rows), then atomic per column
        #pragma unroll
        for (int ni = 0; ni < 4; ++ni) {
            float s = sc[ni], mn = mc[ni];
            s += __shfl_xor(s, 16); s += __shfl_xor(s, 32);
            mn = fminf(mn, __shfl_xor(mn, 16)); mn = fminf(mn, __shfl_xor(mn, 32));
            if (lane < 16) {
                const int j = colBase + wc * 64 + ni * 16 + c;
                atomicAdd(&ap_sum[j], s);
                atomicMin(&an_min[j], __float_as_uint(mn));
            }
        }
    }
}

// ---------------- kernel 3: finalize scalar loss (single block, self-sufficient) ----------------

__global__ __launch_bounds__(1024) void final_kernel(
    const float* __restrict__ ap_sum, const u32* __restrict__ an_min,
    const int* __restrict__ lab, float* __restrict__ out)
{
    __shared__ int cnt[NCLS];
    __shared__ float wsum[16];
    const int t = threadIdx.x;
    if (t < NCLS) cnt[t] = 0;
    __syncthreads();
    for (int i = t; i < B_SZ; i += 1024) atomicAdd(&cnt[lab[i]], 1);
    __syncthreads();
    float v = 0.0f;
    for (int i = t; i < B_SZ; i += 1024) {
        float apm = ap_sum[i] / (float)cnt[lab[i]];
        float anm = __uint_as_float(an_min[i]);
        v += fmaxf(apm - anm + 1.0f, 0.0f);   // MARGIN = 1.0
    }
    #pragma unroll
    for (int off = 1; off < 64; off <<= 1) v += __shfl_xor(v, off);
    if ((t & 63) == 0) wsum[t >> 6] = v;
    __syncthreads();
    if (t == 0) {
        float s = 0.0f;
        #pragma unroll
        for (int w = 0; w < 16; ++w) s += wsum[w];
        out[0] = s;
    }
}

// ---------------- launch ----------------

extern "C" void kernel_launch(void* const* d_in, const int* in_sizes, int n_in,
                              void* d_out, int out_size, void* d_ws, size_t ws_size,
                              hipStream_t stream) {
    const float* inputs = (const float*)d_in[0];
    const int* labels = (const int*)d_in[1];
    float* out = (float*)d_out;

    // workspace layout (~4.3 MB)
    char* ws = (char*)d_ws;
    float* ap_sum = (float*)ws;            // 4096 floats
    u32* an_min = (u32*)(ws + 16384);      // 4096 u32
    float* sq = (float*)(ws + 32768);      // 4096 floats
    u16* bfin = (u16*)(ws + 65536);        // 4096*512 bf16 = 4 MB

    prep_kernel<<<dim3(B_SZ / 4), dim3(256), 0, stream>>>(inputs, bfin, sq, ap_sum, an_min);
    tile_kernel<<<dim3(NBLK), dim3(256), 0, stream>>>(bfin, labels, sq, ap_sum, an_min);
    final_kernel<<<dim3(1), dim3(1024), 0, stream>>>(ap_sum, an_min, labels, out);
}